// Round 12
// baseline (25.313 us; speedup 1.0000x reference)
//
#include <hip/hip_runtime.h>
#include <math.h>

#define MARGIN 0.2f
#define NEG_WEIGHT 0.5f

constexpr int Bc = 64, Nc = 16, Lc = 1024, DH = 64, Ac = 8;
constexpr int NSAMP = Bc * Ac;            // 512
constexpr int CHUNKS = 16;                // chunks per sample
constexpr int RPC = Lc / CHUNKS;          // 64 rows per chunk
constexpr int WPB = 4;                    // wave-tasks per 256-thread block
constexpr int GRID = NSAMP * CHUNKS / WPB;   // 2048 blocks

__device__ __forceinline__ float fast_acosh(float z) {
    // z >= 1 + 1e-7 guaranteed by clamp
    return __logf(z + __builtin_sqrtf(z * z - 1.0f));
}

__device__ __forceinline__ float pdist(float x2, float y2, float d2) {
    x2 = fminf(x2, 0.999999f);
    y2 = fminf(y2, 0.999999f);
    float num = 2.0f * d2;
    float den = (1.0f - x2) * (1.0f - y2);
    float ratio = num * __builtin_amdgcn_rcpf(fmaxf(den, 1e-15f));
    float z = 1.0f + fmaxf(ratio, 1.0f + 1e-7f);
    return fast_acosh(z);
}

// R11 exactly, ONE change: __launch_bounds__(256, 8) — force <=64 VGPR so
// occupancy reaches 8 waves/SIMD (32 waves/CU), doubling latency hiding.
__global__ __launch_bounds__(256, 8) void sample_kernel(
    const float* __restrict__ h_curr,
    const float* __restrict__ demo_h,
    const int*   __restrict__ align_idx,
    const int*   __restrict__ lookahead_p,
    float* __restrict__ wneg,    // [CHUNKS][NSAMP] hinge sums
    float* __restrict__ wpos)    // [NSAMP] d_pos (0 if invalid)
{
    const int tid  = threadIdx.x;
    const int task = (tid >> 6) * GRID + blockIdx.x;   // de-clustered mapping
    const int s    = task >> 4;        // sample 0..511
    const int c    = task & 15;        // chunk  0..15
    const int b    = s >> 3;           // s / Ac
    const int lane = tid & 63;
    const int quad = lane & 3;
    const int rg   = lane >> 2;        // 0..15

    const int n0 = align_idx[s * 2 + 0];
    const int l0 = align_idx[s * 2 + 1];
    const int lk = lookahead_p[0];
    const int lt = l0 + lk;
    const bool valid = (lt >= 0) && (lt < Lc);

    if (!valid) {
        if (lane == 0) {
            wneg[c * NSAMP + s] = 0.0f;
            if (c == 0) wpos[s] = 0.0f;
        }
        return;
    }

    // chunks whose rows are all <= lt contribute nothing — skip the 16 KB read
    const bool dead = (c * RPC + (RPC - 1)) <= lt;
    if (dead && c != 0) {
        if (lane == 0) wneg[c * NSAMP + s] = 0.0f;
        return;
    }

    const int lt_c = min(max(lt, 0), Lc - 1);

    const float* __restrict__ xrow = h_curr + (size_t)b * DH + quad * 16;
    const float* __restrict__ seq  = demo_h + (((size_t)b * Nc + (size_t)n0) * Lc) * DH;

    // x fragment: 16 dims per lane
    float4 xv[4];
    #pragma unroll
    for (int j = 0; j < 4; ++j)
        xv[j] = *reinterpret_cast<const float4*>(xrow + j * 4);

    float x2 = 0.0f;
    #pragma unroll
    for (int j = 0; j < 4; ++j) {
        x2 = fmaf(xv[j].x, xv[j].x, x2);
        x2 = fmaf(xv[j].y, xv[j].y, x2);
        x2 = fmaf(xv[j].z, xv[j].z, x2);
        x2 = fmaf(xv[j].w, xv[j].w, x2);
    }
    x2 += __shfl_xor(x2, 1, 64);
    x2 += __shfl_xor(x2, 2, 64);   // uniform within each quad-group

    // d_pos from row lt_c
    float d_pos;
    {
        const float* rowp = seq + (size_t)lt_c * DH + quad * 16;
        float d2 = 0.0f, y2 = 0.0f;
        #pragma unroll
        for (int j = 0; j < 4; ++j) {
            float4 yv = *reinterpret_cast<const float4*>(rowp + j * 4);
            float dx = xv[j].x - yv.x, dy = xv[j].y - yv.y;
            float dz = xv[j].z - yv.z, dw = xv[j].w - yv.w;
            d2 = fmaf(dx, dx, d2); d2 = fmaf(dy, dy, d2);
            d2 = fmaf(dz, dz, d2); d2 = fmaf(dw, dw, d2);
            y2 = fmaf(yv.x, yv.x, y2); y2 = fmaf(yv.y, yv.y, y2);
            y2 = fmaf(yv.z, yv.z, y2); y2 = fmaf(yv.w, yv.w, y2);
        }
        d2 += __shfl_xor(d2, 1, 64); d2 += __shfl_xor(d2, 2, 64);
        y2 += __shfl_xor(y2, 1, 64); y2 += __shfl_xor(y2, 2, 64);
        d_pos = pdist(x2, y2, d2);
    }

    if (dead) {   // only possible for c == 0: write d_pos, zero hinge, exit
        if (lane == 0) {
            wneg[c * NSAMP + s] = 0.0f;
            wpos[s] = d_pos;
        }
        return;
    }

    // negatives: 64 rows of this chunk, 16 rows per pass (one per row-group)
    float hinge_acc = 0.0f;
    #pragma unroll
    for (int it = 0; it < 4; ++it) {
        const int row = c * RPC + it * 16 + rg;
        const float* rowp = seq + (size_t)row * DH + quad * 16;
        float d2 = 0.0f, y2 = 0.0f;
        #pragma unroll
        for (int j = 0; j < 4; ++j) {
            float4 yv = *reinterpret_cast<const float4*>(rowp + j * 4);
            float dx = xv[j].x - yv.x, dy = xv[j].y - yv.y;
            float dz = xv[j].z - yv.z, dw = xv[j].w - yv.w;
            d2 = fmaf(dx, dx, d2); d2 = fmaf(dy, dy, d2);
            d2 = fmaf(dz, dz, d2); d2 = fmaf(dw, dw, d2);
            y2 = fmaf(yv.x, yv.x, y2); y2 = fmaf(yv.y, yv.y, y2);
            y2 = fmaf(yv.z, yv.z, y2); y2 = fmaf(yv.w, yv.w, y2);
        }
        d2 += __shfl_xor(d2, 1, 64); d2 += __shfl_xor(d2, 2, 64);
        y2 += __shfl_xor(y2, 1, 64); y2 += __shfl_xor(y2, 2, 64);
        float dneg = pdist(x2, y2, d2);
        if (row > lt)
            hinge_acc += fmaxf(MARGIN - dneg + d_pos, 0.0f);
    }

    // hinge_acc uniform within each quad; sum across the 16 row-groups
    hinge_acc += __shfl_xor(hinge_acc, 4, 64);
    hinge_acc += __shfl_xor(hinge_acc, 8, 64);
    hinge_acc += __shfl_xor(hinge_acc, 16, 64);
    hinge_acc += __shfl_xor(hinge_acc, 32, 64);

    if (lane == 0) {
        wneg[c * NSAMP + s] = hinge_acc;
        if (c == 0) wpos[s] = d_pos;
    }
}

// 512 threads (8 waves), 1 thread per sample; wneg reads fully coalesced.
__global__ __launch_bounds__(512) void reduce_kernel(
    const float* __restrict__ wneg,
    const float* __restrict__ wpos,
    const int*   __restrict__ align_idx,
    const int*   __restrict__ lookahead_p,
    float* __restrict__ out)
{
    const int tid = threadIdx.x;       // == sample id
    const int lk = lookahead_p[0];

    const int lt = align_idx[tid * 2 + 1] + lk;
    const bool v = (lt >= 0) && (lt < Lc);

    float h = 0.0f;
    #pragma unroll
    for (int c = 0; c < CHUNKS; ++c)
        h += wneg[c * NSAMP + tid];    // consecutive lanes -> consecutive addrs

    const float cnt = v ? (float)(Lc - 1 - lt) : 0.0f;   // #rows > lt
    const float has_neg = (cnt > 0.0f) ? 1.0f : 0.0f;

    float pn = wpos[tid];
    float pv = v ? 1.0f : 0.0f;
    float nn = (h / fmaxf(cnt, 1.0f)) * has_neg;
    float nc = has_neg;

    #pragma unroll
    for (int m = 1; m < 64; m <<= 1) {
        pn += __shfl_xor(pn, m, 64);
        pv += __shfl_xor(pv, m, 64);
        nn += __shfl_xor(nn, m, 64);
        nc += __shfl_xor(nc, m, 64);
    }

    __shared__ float4 sh[8];
    if ((tid & 63) == 0) sh[tid >> 6] = make_float4(pn, pv, nn, nc);
    __syncthreads();
    if (tid == 0) {
        float4 a = sh[0];
        #pragma unroll
        for (int w = 1; w < 8; ++w) {
            a.x += sh[w].x; a.y += sh[w].y; a.z += sh[w].z; a.w += sh[w].w;
        }
        const float pos_term = a.x / fmaxf(a.y, 1.0f);
        const float neg_term = a.z / fmaxf(a.w, 1.0f);
        out[0] = pos_term + NEG_WEIGHT * neg_term;
    }
}

extern "C" void kernel_launch(void* const* d_in, const int* in_sizes, int n_in,
                              void* d_out, int out_size, void* d_ws, size_t ws_size,
                              hipStream_t stream) {
    const float* h_curr    = (const float*)d_in[0];
    const float* demo_h    = (const float*)d_in[1];
    const int*   align_idx = (const int*)d_in[2];
    const int*   lookahead = (const int*)d_in[3];
    float* out  = (float*)d_out;
    float* wneg = (float*)d_ws;                       // CHUNKS*NSAMP floats
    float* wpos = (float*)d_ws + CHUNKS * NSAMP;      // NSAMP floats

    sample_kernel<<<GRID, 256, 0, stream>>>(
        h_curr, demo_h, align_idx, lookahead, wneg, wpos);
    reduce_kernel<<<1, 512, 0, stream>>>(wneg, wpos, align_idx, lookahead, out);
}

// Round 13
// 23.950 us; speedup vs baseline: 1.0569x; 1.0569x over previous
//
#include <hip/hip_runtime.h>
#include <math.h>

#define MARGIN 0.2f
#define NEG_WEIGHT 0.5f

constexpr int Bc = 64, Nc = 16, Lc = 1024, DH = 64, Ac = 8;
constexpr int NSAMP = Bc * Ac;            // 512
constexpr int CHUNKS = 16;                // chunks per sample
constexpr int RPC = Lc / CHUNKS;          // 64 rows per chunk
constexpr int WPB = 4;                    // wave-tasks per 256-thread block
constexpr int GRID = NSAMP * CHUNKS / WPB;   // 2048 blocks

__device__ __forceinline__ float fast_acosh(float z) {
    // z >= 1 + 1e-7 guaranteed by clamp
    return __logf(z + __builtin_sqrtf(z * z - 1.0f));
}

__device__ __forceinline__ float pdist(float x2, float y2, float d2) {
    x2 = fminf(x2, 0.999999f);
    y2 = fminf(y2, 0.999999f);
    float num = 2.0f * d2;
    float den = (1.0f - x2) * (1.0f - y2);
    float ratio = num * __builtin_amdgcn_rcpf(fmaxf(den, 1e-15f));
    float z = 1.0f + fmaxf(ratio, 1.0f + 1e-7f);
    return fast_acosh(z);
}

// R11 optimum (best measured: 24.2 us). Per-wave quad layout; 4 wave-tasks
// per 256-thread block with de-clustered task mapping; algebraic skip of
// chunks entirely <= lt; closed-form cnt in the reduce.
// lane layout: quad = lane&3 owns dims [quad*16,+16); rg = lane>>2 owns a row
__global__ __launch_bounds__(256) void sample_kernel(
    const float* __restrict__ h_curr,
    const float* __restrict__ demo_h,
    const int*   __restrict__ align_idx,
    const int*   __restrict__ lookahead_p,
    float* __restrict__ wneg,    // [CHUNKS][NSAMP] hinge sums
    float* __restrict__ wpos)    // [NSAMP] d_pos (0 if invalid)
{
    const int tid  = threadIdx.x;
    const int task = (tid >> 6) * GRID + blockIdx.x;   // de-clustered mapping
    const int s    = task >> 4;        // sample 0..511
    const int c    = task & 15;        // chunk  0..15
    const int b    = s >> 3;           // s / Ac
    const int lane = tid & 63;
    const int quad = lane & 3;
    const int rg   = lane >> 2;        // 0..15

    const int n0 = align_idx[s * 2 + 0];
    const int l0 = align_idx[s * 2 + 1];
    const int lk = lookahead_p[0];
    const int lt = l0 + lk;
    const bool valid = (lt >= 0) && (lt < Lc);

    if (!valid) {
        if (lane == 0) {
            wneg[c * NSAMP + s] = 0.0f;
            if (c == 0) wpos[s] = 0.0f;
        }
        return;
    }

    // chunks whose rows are all <= lt contribute nothing — skip the 16 KB read
    const bool dead = (c * RPC + (RPC - 1)) <= lt;
    if (dead && c != 0) {
        if (lane == 0) wneg[c * NSAMP + s] = 0.0f;
        return;
    }

    const int lt_c = min(max(lt, 0), Lc - 1);

    const float* __restrict__ xrow = h_curr + (size_t)b * DH + quad * 16;
    const float* __restrict__ seq  = demo_h + (((size_t)b * Nc + (size_t)n0) * Lc) * DH;

    // x fragment: 16 dims per lane
    float4 xv[4];
    #pragma unroll
    for (int j = 0; j < 4; ++j)
        xv[j] = *reinterpret_cast<const float4*>(xrow + j * 4);

    float x2 = 0.0f;
    #pragma unroll
    for (int j = 0; j < 4; ++j) {
        x2 = fmaf(xv[j].x, xv[j].x, x2);
        x2 = fmaf(xv[j].y, xv[j].y, x2);
        x2 = fmaf(xv[j].z, xv[j].z, x2);
        x2 = fmaf(xv[j].w, xv[j].w, x2);
    }
    x2 += __shfl_xor(x2, 1, 64);
    x2 += __shfl_xor(x2, 2, 64);   // uniform within each quad-group

    // d_pos from row lt_c
    float d_pos;
    {
        const float* rowp = seq + (size_t)lt_c * DH + quad * 16;
        float d2 = 0.0f, y2 = 0.0f;
        #pragma unroll
        for (int j = 0; j < 4; ++j) {
            float4 yv = *reinterpret_cast<const float4*>(rowp + j * 4);
            float dx = xv[j].x - yv.x, dy = xv[j].y - yv.y;
            float dz = xv[j].z - yv.z, dw = xv[j].w - yv.w;
            d2 = fmaf(dx, dx, d2); d2 = fmaf(dy, dy, d2);
            d2 = fmaf(dz, dz, d2); d2 = fmaf(dw, dw, d2);
            y2 = fmaf(yv.x, yv.x, y2); y2 = fmaf(yv.y, yv.y, y2);
            y2 = fmaf(yv.z, yv.z, y2); y2 = fmaf(yv.w, yv.w, y2);
        }
        d2 += __shfl_xor(d2, 1, 64); d2 += __shfl_xor(d2, 2, 64);
        y2 += __shfl_xor(y2, 1, 64); y2 += __shfl_xor(y2, 2, 64);
        d_pos = pdist(x2, y2, d2);
    }

    if (dead) {   // only possible for c == 0: write d_pos, zero hinge, exit
        if (lane == 0) {
            wneg[c * NSAMP + s] = 0.0f;
            wpos[s] = d_pos;
        }
        return;
    }

    // negatives: 64 rows of this chunk, 16 rows per pass (one per row-group)
    float hinge_acc = 0.0f;
    #pragma unroll
    for (int it = 0; it < 4; ++it) {
        const int row = c * RPC + it * 16 + rg;
        const float* rowp = seq + (size_t)row * DH + quad * 16;
        float d2 = 0.0f, y2 = 0.0f;
        #pragma unroll
        for (int j = 0; j < 4; ++j) {
            float4 yv = *reinterpret_cast<const float4*>(rowp + j * 4);
            float dx = xv[j].x - yv.x, dy = xv[j].y - yv.y;
            float dz = xv[j].z - yv.z, dw = xv[j].w - yv.w;
            d2 = fmaf(dx, dx, d2); d2 = fmaf(dy, dy, d2);
            d2 = fmaf(dz, dz, d2); d2 = fmaf(dw, dw, d2);
            y2 = fmaf(yv.x, yv.x, y2); y2 = fmaf(yv.y, yv.y, y2);
            y2 = fmaf(yv.z, yv.z, y2); y2 = fmaf(yv.w, yv.w, y2);
        }
        d2 += __shfl_xor(d2, 1, 64); d2 += __shfl_xor(d2, 2, 64);
        y2 += __shfl_xor(y2, 1, 64); y2 += __shfl_xor(y2, 2, 64);
        float dneg = pdist(x2, y2, d2);
        if (row > lt)
            hinge_acc += fmaxf(MARGIN - dneg + d_pos, 0.0f);
    }

    // hinge_acc uniform within each quad; sum across the 16 row-groups
    hinge_acc += __shfl_xor(hinge_acc, 4, 64);
    hinge_acc += __shfl_xor(hinge_acc, 8, 64);
    hinge_acc += __shfl_xor(hinge_acc, 16, 64);
    hinge_acc += __shfl_xor(hinge_acc, 32, 64);

    if (lane == 0) {
        wneg[c * NSAMP + s] = hinge_acc;
        if (c == 0) wpos[s] = d_pos;
    }
}

// 512 threads (8 waves), 1 thread per sample; wneg reads fully coalesced.
__global__ __launch_bounds__(512) void reduce_kernel(
    const float* __restrict__ wneg,
    const float* __restrict__ wpos,
    const int*   __restrict__ align_idx,
    const int*   __restrict__ lookahead_p,
    float* __restrict__ out)
{
    const int tid = threadIdx.x;       // == sample id
    const int lk = lookahead_p[0];

    const int lt = align_idx[tid * 2 + 1] + lk;
    const bool v = (lt >= 0) && (lt < Lc);

    float h = 0.0f;
    #pragma unroll
    for (int c = 0; c < CHUNKS; ++c)
        h += wneg[c * NSAMP + tid];    // consecutive lanes -> consecutive addrs

    const float cnt = v ? (float)(Lc - 1 - lt) : 0.0f;   // #rows > lt
    const float has_neg = (cnt > 0.0f) ? 1.0f : 0.0f;

    float pn = wpos[tid];
    float pv = v ? 1.0f : 0.0f;
    float nn = (h / fmaxf(cnt, 1.0f)) * has_neg;
    float nc = has_neg;

    #pragma unroll
    for (int m = 1; m < 64; m <<= 1) {
        pn += __shfl_xor(pn, m, 64);
        pv += __shfl_xor(pv, m, 64);
        nn += __shfl_xor(nn, m, 64);
        nc += __shfl_xor(nc, m, 64);
    }

    __shared__ float4 sh[8];
    if ((tid & 63) == 0) sh[tid >> 6] = make_float4(pn, pv, nn, nc);
    __syncthreads();
    if (tid == 0) {
        float4 a = sh[0];
        #pragma unroll
        for (int w = 1; w < 8; ++w) {
            a.x += sh[w].x; a.y += sh[w].y; a.z += sh[w].z; a.w += sh[w].w;
        }
        const float pos_term = a.x / fmaxf(a.y, 1.0f);
        const float neg_term = a.z / fmaxf(a.w, 1.0f);
        out[0] = pos_term + NEG_WEIGHT * neg_term;
    }
}

extern "C" void kernel_launch(void* const* d_in, const int* in_sizes, int n_in,
                              void* d_out, int out_size, void* d_ws, size_t ws_size,
                              hipStream_t stream) {
    const float* h_curr    = (const float*)d_in[0];
    const float* demo_h    = (const float*)d_in[1];
    const int*   align_idx = (const int*)d_in[2];
    const int*   lookahead = (const int*)d_in[3];
    float* out  = (float*)d_out;
    float* wneg = (float*)d_ws;                       // CHUNKS*NSAMP floats
    float* wpos = (float*)d_ws + CHUNKS * NSAMP;      // NSAMP floats

    sample_kernel<<<GRID, 256, 0, stream>>>(
        h_curr, demo_h, align_idx, lookahead, wneg, wpos);
    reduce_kernel<<<1, 512, 0, stream>>>(wneg, wpos, align_idx, lookahead, out);
}